// Round 9
// baseline (835.335 us; speedup 1.0000x reference)
//
#include <hip/hip_runtime.h>
#include <hip/hip_bf16.h>
#include <stdint.h>

typedef __attribute__((ext_vector_type(4))) float f32x4;
typedef __attribute__((ext_vector_type(8))) short s16x8;
typedef __attribute__((ext_vector_type(4))) unsigned short u16x4;

#define EPSBN 1e-5f

__device__ __forceinline__ float bf2f(unsigned short u) {
  union { unsigned int i; float f; } w; w.i = ((unsigned int)u) << 16; return w.f;
}
__device__ __forceinline__ unsigned short f2bf(float f) {
  __hip_bfloat16 h = __float2bfloat16(f);   // RNE
  unsigned short u; __builtin_memcpy(&u, &h, 2); return u;
}
__device__ __forceinline__ void gld_lds16(const void* g, void* l) {
  __builtin_amdgcn_global_load_lds(
      (const __attribute__((address_space(1))) void*)(g),
      (__attribute__((address_space(3))) void*)(l), 16, 0, 0);
}

// ---------------- graph prep ----------------
__global__ void k_count(const int* __restrict__ dst, unsigned* __restrict__ deg, int E) {
  int i = blockIdx.x * 256 + threadIdx.x;
  if (i < E) atomicAdd(&deg[dst[i]], 1u);
}
__global__ void k_prep2(const unsigned* __restrict__ deg, float* __restrict__ dinv,
                        unsigned* __restrict__ bsum, int n) {
  __shared__ unsigned s[256];
  int t = threadIdx.x, i = blockIdx.x * 256 + t;
  unsigned d = (i < n) ? deg[i] + 1u : 0u;
  if (i < n) dinv[i] = rsqrtf((float)d);
  s[t] = d;
  __syncthreads();
  for (int st = 128; st > 0; st >>= 1) {
    if (t < st) s[t] += s[t + st];
    __syncthreads();
  }
  if (t == 0) bsum[blockIdx.x] = s[0];
}
__global__ void k_scan_top(const unsigned* __restrict__ bsum, unsigned* __restrict__ bpre,
                           int nb, unsigned* __restrict__ offs, int n) {
  __shared__ unsigned s[256];
  int t = threadIdx.x;
  unsigned v = (t < nb) ? bsum[t] : 0u;
  s[t] = v; __syncthreads();
  for (int d = 1; d < 256; d <<= 1) {
    unsigned a = (t >= d) ? s[t - d] : 0u;
    __syncthreads();
    s[t] += a;
    __syncthreads();
  }
  bpre[t] = s[t] - v;                    // exclusive
  if (t == 255) offs[n] = s[255];        // total = E + n
}
__global__ void k_scan_fin(const unsigned* __restrict__ deg, const unsigned* __restrict__ bpre,
                           unsigned* __restrict__ offs, unsigned* __restrict__ cur, int n) {
  __shared__ unsigned s[256];
  int t = threadIdx.x, i = blockIdx.x * 256 + t;
  unsigned v = (i < n) ? deg[i] + 1u : 0u;
  s[t] = v; __syncthreads();
  for (int d = 1; d < 256; d <<= 1) {
    unsigned a = (t >= d) ? s[t - d] : 0u;
    __syncthreads();
    s[t] += a;
    __syncthreads();
  }
  if (i < n) {
    unsigned o = bpre[blockIdx.x] + s[t] - v;
    offs[i] = o; cur[i] = o;
  }
}
__global__ void k_fill(const int* __restrict__ src, const int* __restrict__ dst,
                       unsigned* __restrict__ cur, unsigned short* __restrict__ ewp,
                       int E, int n) {
  int i = blockIdx.x * 256 + threadIdx.x;
  int s, d;
  if (i < E)          { s = src[i]; d = dst[i]; }
  else if (i < E + n) { s = d = i - E; }        // self-loop
  else return;
  unsigned p = atomicAdd(&cur[d], 1u);
  ewp[p] = (unsigned short)s;
}
__global__ __launch_bounds__(256) void k_sortw(const unsigned* __restrict__ offs,
                                               unsigned short* __restrict__ ewp, int nN) {
  int wv = (blockIdx.x * 256 + threadIdx.x) >> 6;
  int lane = threadIdx.x & 63;
  if (wv >= nN) return;
  unsigned beg = offs[wv], end = offs[wv + 1];
  int len = (int)(end - beg);
  if (len > 64) return;                  // rare: leave unsorted (correct)
  int k = (lane < len) ? (int)ewp[beg + lane] : 0x10000;
#pragma unroll
  for (int size = 2; size <= 64; size <<= 1) {
#pragma unroll
    for (int stride = size >> 1; stride > 0; stride >>= 1) {
      int other = __shfl_xor(k, stride);
      bool up = (lane & size) == 0;
      bool lower = (lane & stride) == 0;
      k = (lower == up) ? min(k, other) : max(k, other);
    }
  }
  if (lane < len) ewp[beg + lane] = (unsigned short)k;
}
__global__ void k_wt3(const float* __restrict__ W1, unsigned short* __restrict__ Wt1,
                      const float* __restrict__ W2, unsigned short* __restrict__ Wt2,
                      const float* __restrict__ W3, unsigned short* __restrict__ Wt3,
                      unsigned short* __restrict__ bufA, unsigned short* __restrict__ bufB,
                      int nN) {
  const int n1 = 256 * 1280, n2 = 256 * 256, n3 = 512 * 256;
  int idx = blockIdx.x * 256 + threadIdx.x;
  if (idx >= n1 + n2 + n3) {
    int z = idx - (n1 + n2 + n3);
    if (z < 256)      bufA[(size_t)nN * 256 + z] = 0;
    else if (z < 512) bufB[(size_t)nN * 256 + (z - 256)] = 0;
    return;
  }
  const float* W; unsigned short* Wt; int K, N;
  if (idx < n1)           { W = W1; Wt = Wt1; K = 1280; N = 256; }
  else if (idx < n1 + n2) { W = W2; Wt = Wt2; K = 256;  N = 256; idx -= n1; }
  else                    { W = W3; Wt = Wt3; K = 256;  N = 500; idx -= n1 + n2; }
  int nn = idx / K, k = idx - nn * K;
  float v = (nn < N) ? W[(size_t)k * N + nn] : 0.f;
  Wt[idx] = f2bf(v);
}

// ---------------- GEMM (bf16 A): C[M,N] = A[M,K] * Bt[N,K]^T ----------------
// 512 threads, 8 waves (2x4), tile 128x256, BK=64. LDS 48 KB -> 3 blocks/CU.
// OUTMODE 0: bf16 out *dinv[row]; 1: fp32 out + bias.
#define BM 128
#define BN 256
#define BK 64

template<int OUTMODE>
__global__ __launch_bounds__(512, 6) void k_gemm(
    const unsigned short* __restrict__ Au, const unsigned short* __restrict__ Bt,
    void* __restrict__ Coutv, const float* __restrict__ bias,
    const float* __restrict__ dinv, int M, int N, int K, int NT)
{
  __shared__ __align__(16) unsigned short As[BM * BK];   // 16 KB
  __shared__ __align__(16) unsigned short Bs[BN * BK];   // 32 KB

  int d = blockIdx.x;
  int nt = (NT == 2) ? (d & 1) : 0;
  int mt = (NT == 2) ? (d >> 1) : d;
  int m0 = mt * BM, n0 = nt * BN;

  int tid = threadIdx.x, lane = tid & 63, wave = tid >> 6;
  int wm = wave >> 2, wn = wave & 3;
  int l15 = lane & 15, l4 = lane >> 4;

  f32x4 acc[4][4];
#pragma unroll
  for (int i = 0; i < 4; ++i)
#pragma unroll
    for (int j = 0; j < 4; ++j) acc[i][j] = 0.f;

  // A: 1024 chunks (8 per 128B row), 2/thread. B: 2048 chunks, 4/thread.
  int arow[2], acg[2];
#pragma unroll
  for (int i = 0; i < 2; ++i) {
    int ci = i * 512 + tid;
    arow[i] = ci >> 3;
    acg[i] = (ci & 7) ^ (arow[i] & 7);
  }
  int brow[4], bcg[4];
#pragma unroll
  for (int i = 0; i < 4; ++i) {
    int ci = i * 512 + tid;
    brow[i] = ci >> 3;
    bcg[i] = (ci & 7) ^ (brow[i] & 7);
  }

  int nk = K / BK;
  for (int kt = 0; kt < nk; ++kt) {
    __syncthreads();
#pragma unroll
    for (int i = 0; i < 2; ++i) {
      int gr = m0 + arow[i]; gr = gr < M ? gr : M - 1;
      gld_lds16(Au + (size_t)gr * K + kt * BK + acg[i] * 8,
                As + (size_t)(i * 512 + wave * 64) * 8);
    }
#pragma unroll
    for (int i = 0; i < 4; ++i) {
      int gn = n0 + brow[i];
      gld_lds16(Bt + (size_t)gn * K + kt * BK + bcg[i] * 8,
                Bs + (size_t)(i * 512 + wave * 64) * 8);
    }
    __syncthreads();

#pragma unroll
    for (int ks = 0; ks < 2; ++ks) {
      s16x8 af[4], bf[4];
#pragma unroll
      for (int f = 0; f < 4; ++f) {
        int r = wm * 64 + f * 16 + l15;
        int ca = (ks * 4 + l4) ^ (r & 7);
        af[f] = *(const s16x8*)(As + r * 64 + ca * 8);
        int nloc = wn * 64 + f * 16 + l15;
        int cb = (ks * 4 + l4) ^ (nloc & 7);
        bf[f] = *(const s16x8*)(Bs + nloc * 64 + cb * 8);
      }
#pragma unroll
      for (int fm = 0; fm < 4; ++fm)
#pragma unroll
        for (int fn = 0; fn < 4; ++fn)
          acc[fm][fn] = __builtin_amdgcn_mfma_f32_16x16x32_bf16(af[fm], bf[fn], acc[fm][fn], 0, 0, 0);
    }
  }

#pragma unroll
  for (int fm = 0; fm < 4; ++fm) {
#pragma unroll
    for (int r = 0; r < 4; ++r) {
      int row = m0 + wm * 64 + fm * 16 + l4 * 4 + r;
      float dsc = (OUTMODE == 0 && row < M) ? dinv[row] : 0.f;
#pragma unroll
      for (int fn = 0; fn < 4; ++fn) {
        int col = n0 + wn * 64 + fn * 16 + l15;
        if (row < M && col < N) {
          if (OUTMODE == 1)
            ((float*)Coutv)[(size_t)row * N + col] = acc[fm][fn][r] + bias[col];
          else
            ((unsigned short*)Coutv)[(size_t)row * N + col] = f2bf(acc[fm][fn][r] * dsc);
        }
      }
    }
  }
}

// ------- GEMM layer1: A fp32 staged via global_load_lds (full-bank swizzle), out bf16*dinv -------
// 512 threads, tile 128x256 (NT=1), LDS 64 KB -> 2 blocks/CU. A staged exactly once.
__global__ __launch_bounds__(512, 4) void k_gemmF(
    const float* __restrict__ Af, const unsigned short* __restrict__ Bt,
    unsigned short* __restrict__ Cout, const float* __restrict__ dinv,
    int M, int N, int K)
{
  __shared__ __align__(16) float As[BM * BK];            // 32 KB fp32
  __shared__ __align__(16) unsigned short Bs[BN * BK];   // 32 KB

  int mt = blockIdx.x;
  int m0 = mt * BM, n0 = 0;

  int tid = threadIdx.x, lane = tid & 63, wave = tid >> 6;
  int wm = wave >> 2, wn = wave & 3;
  int l15 = lane & 15, l4 = lane >> 4;

  f32x4 acc[4][4];
#pragma unroll
  for (int i = 0; i < 4; ++i)
#pragma unroll
    for (int j = 0; j < 4; ++j) acc[i][j] = 0.f;

  // A: 2048 chunks (16 per 256B row), 4/thread; swizzle s(row) covers bit0 for full bank spread
  int arow[4], acs[4];
#pragma unroll
  for (int i = 0; i < 4; ++i) {
    int ci = i * 512 + tid;
    arow[i] = ci >> 4;
    int s = ((arow[i] & 7) << 1) | ((arow[i] >> 3) & 1);
    acs[i] = (ci & 15) ^ s;
  }
  int brow[4], bcg[4];
#pragma unroll
  for (int i = 0; i < 4; ++i) {
    int ci = i * 512 + tid;
    brow[i] = ci >> 3;
    bcg[i] = (ci & 7) ^ (brow[i] & 7);
  }

  int nk = K / BK;
  for (int kt = 0; kt < nk; ++kt) {
    __syncthreads();
#pragma unroll
    for (int i = 0; i < 4; ++i) {
      int gr = m0 + arow[i]; gr = gr < M ? gr : M - 1;
      gld_lds16(Af + (size_t)gr * K + kt * BK + acs[i] * 4,
                As + (size_t)(i * 512 + wave * 64) * 4);
    }
#pragma unroll
    for (int i = 0; i < 4; ++i) {
      int gn = n0 + brow[i];
      gld_lds16(Bt + (size_t)gn * K + kt * BK + bcg[i] * 8,
                Bs + (size_t)(i * 512 + wave * 64) * 8);
    }
    __syncthreads();

#pragma unroll
    for (int ks = 0; ks < 2; ++ks) {
      s16x8 af[4], bf[4];
#pragma unroll
      for (int f = 0; f < 4; ++f) {
        int r = wm * 64 + f * 16 + l15;
        int s = ((r & 7) << 1) | ((r >> 3) & 1);
        int gc0 = ks * 8 + 2 * l4;
        f32x4 a0 = *(const f32x4*)(As + r * 64 + (gc0 ^ s) * 4);
        f32x4 a1 = *(const f32x4*)(As + r * 64 + ((gc0 + 1) ^ s) * 4);
        s16x8 pk;
        pk[0] = (short)f2bf(a0[0]); pk[1] = (short)f2bf(a0[1]);
        pk[2] = (short)f2bf(a0[2]); pk[3] = (short)f2bf(a0[3]);
        pk[4] = (short)f2bf(a1[0]); pk[5] = (short)f2bf(a1[1]);
        pk[6] = (short)f2bf(a1[2]); pk[7] = (short)f2bf(a1[3]);
        af[f] = pk;
        int nloc = wn * 64 + f * 16 + l15;
        int cb = (ks * 4 + l4) ^ (nloc & 7);
        bf[f] = *(const s16x8*)(Bs + nloc * 64 + cb * 8);
      }
#pragma unroll
      for (int fm = 0; fm < 4; ++fm)
#pragma unroll
        for (int fn = 0; fn < 4; ++fn)
          acc[fm][fn] = __builtin_amdgcn_mfma_f32_16x16x32_bf16(af[fm], bf[fn], acc[fm][fn], 0, 0, 0);
    }
  }

#pragma unroll
  for (int fm = 0; fm < 4; ++fm) {
#pragma unroll
    for (int r = 0; r < 4; ++r) {
      int row = m0 + wm * 64 + fm * 16 + l4 * 4 + r;
      float dsc = (row < M) ? dinv[row] : 0.f;
#pragma unroll
      for (int fn = 0; fn < 4; ++fn) {
        int col = n0 + wn * 64 + fn * 16 + l15;
        if (row < M && col < N)
          Cout[(size_t)row * N + col] = f2bf(acc[fm][fn][r] * dsc);
      }
    }
  }
}

// -------- aggregation (C=256), 16-deep pipelined row gathers, pre-scaled h --------
template<int BNRELU, int SCALEOUT>
__global__ __launch_bounds__(256) void k_agg(
    const unsigned short* __restrict__ h, const unsigned short* __restrict__ ewp,
    const unsigned* __restrict__ offs, const float* __restrict__ dinv,
    const float* __restrict__ bias, const float* __restrict__ gam,
    const float* __restrict__ bet, const float* __restrict__ mea,
    const float* __restrict__ var, unsigned short* __restrict__ outp, int nN)
{
  int wave = threadIdx.x >> 6, lane = threadIdx.x & 63;
  int v = blockIdx.x * 4 + wave;
  if (v >= nN) return;
  unsigned beg = offs[v], end = offs[v + 1];
  int len = (int)(end - beg);
  float dv = dinv[v];
  const unsigned short* hb = h + lane * 4;
  float a0 = 0, a1 = 0, a2 = 0, a3 = 0;

  for (int base = 0; base < len; base += 64) {
    int m = min(64, len - base);
    int myp = (lane < m) ? (int)ewp[beg + base + lane] : nN;   // pad -> zero row
    int ng = (m + 15) >> 4;

    u16x4 q[16];
#pragma unroll
    for (int r = 0; r < 16; ++r) {
      int s = __shfl(myp, r);
      q[r] = *(const u16x4*)(hb + (size_t)s * 256);
    }
    for (int g = 1; g < ng; ++g) {
      u16x4 q2[16];
#pragma unroll
      for (int r = 0; r < 16; ++r) {
        int s = __shfl(myp, g * 16 + r);
        q2[r] = *(const u16x4*)(hb + (size_t)s * 256);
      }
#pragma unroll
      for (int r = 0; r < 16; ++r) {
        a0 += bf2f(q[r][0]); a1 += bf2f(q[r][1]);
        a2 += bf2f(q[r][2]); a3 += bf2f(q[r][3]);
      }
#pragma unroll
      for (int r = 0; r < 16; ++r) q[r] = q2[r];
    }
#pragma unroll
    for (int r = 0; r < 16; ++r) {
      a0 += bf2f(q[r][0]); a1 += bf2f(q[r][1]);
      a2 += bf2f(q[r][2]); a3 += bf2f(q[r][3]);
    }
  }

  float va[4] = {a0, a1, a2, a3};
  int ch0 = lane * 4;
#pragma unroll
  for (int j = 0; j < 4; ++j) {
    int ch = ch0 + j;
    float val = va[j] * dv;                    // dst-side norm factor
    if (BNRELU) {
      val += bias[ch];
      val = (val - mea[ch]) * rsqrtf(var[ch] + EPSBN) * gam[ch] + bet[ch];
      val = fmaxf(val, 0.f);
    }
    if (SCALEOUT) val *= dv;                   // pre-scale for the NEXT aggregation
    outp[(size_t)v * 256 + ch] = f2bf(val);
  }
}

// ---------------- launch ----------------
extern "C" void kernel_launch(void* const* d_in, const int* in_sizes, int n_in,
                              void* d_out, int out_size, void* d_ws, size_t ws_size,
                              hipStream_t stream) {
  const float* x   = (const float*)d_in[0];
  const int*   ei  = (const int*)d_in[1];
  const float* W1  = (const float*)d_in[2];
  const float* b1  = (const float*)d_in[3];
  const float* g1  = (const float*)d_in[4];
  const float* be1 = (const float*)d_in[5];
  const float* m1  = (const float*)d_in[6];
  const float* v1  = (const float*)d_in[7];
  const float* W2  = (const float*)d_in[8];
  const float* b2  = (const float*)d_in[9];
  const float* g2  = (const float*)d_in[10];
  const float* be2 = (const float*)d_in[11];
  const float* m2  = (const float*)d_in[12];
  const float* v2  = (const float*)d_in[13];
  const float* W3  = (const float*)d_in[14];
  const float* b3  = (const float*)d_in[15];

  const int IN = 1280, H = 256, OUT = 500, OUTP = 512;
  int E  = in_sizes[1] / 2;
  int nN = in_sizes[0] / IN;
  const int* srcI = ei;
  const int* dstI = ei + E;

  char* p = (char*)d_ws;
  auto carve = [&](size_t bytes) { char* r = p; p += (bytes + 511) & ~(size_t)511; return r; };
  unsigned short* Wt1 = (unsigned short*)carve((size_t)H * IN * 2);
  unsigned short* Wt2 = (unsigned short*)carve((size_t)H * H * 2);
  unsigned short* Wt3 = (unsigned short*)carve((size_t)OUTP * H * 2);
  unsigned* deg  = (unsigned*)carve((size_t)nN * 4);
  float*    dinv = (float*)carve((size_t)nN * 4);
  unsigned* offs = (unsigned*)carve((size_t)(nN + 1) * 4);
  unsigned* cur  = (unsigned*)carve((size_t)nN * 4);
  unsigned* bsum = (unsigned*)carve(256 * 4);
  unsigned* bpre = (unsigned*)carve(256 * 4);
  unsigned short* ewp = (unsigned short*)carve((size_t)(E + nN) * 2);
  unsigned short* bufA = (unsigned short*)carve((size_t)(nN + 1) * H * 2);  // +1 zero pad row
  unsigned short* bufB = (unsigned short*)carve((size_t)(nN + 1) * H * 2);

  hipMemsetAsync(deg, 0, (size_t)nN * 4, stream);

  int NB = (nN + 255) / 256;
  k_count<<<(E + 255) / 256, 256, 0, stream>>>(dstI, deg, E);
  k_prep2<<<NB, 256, 0, stream>>>(deg, dinv, bsum, nN);
  k_scan_top<<<1, 256, 0, stream>>>(bsum, bpre, NB, offs, nN);
  k_scan_fin<<<NB, 256, 0, stream>>>(deg, bpre, offs, cur, nN);
  k_fill<<<(E + nN + 255) / 256, 256, 0, stream>>>(srcI, dstI, cur, ewp, E, nN);
  k_sortw<<<(nN + 3) / 4, 256, 0, stream>>>(offs, ewp, nN);
  k_wt3<<<(256 * 1280 + 256 * 256 + 512 * 256 + 512 + 255) / 256, 256, 0, stream>>>(
      W1, Wt1, W2, Wt2, W3, Wt3, bufA, bufB, nN);

  int MT = (nN + BM - 1) / BM;          // 391
  int nAgg = (nN + 3) / 4;

  // layer 1:  h1' = (x*W1)*dinv ; act1 = BNReLU(dinv*sum h1' + b1)
  k_gemmF<<<MT, 512, 0, stream>>>(x, Wt1, bufA, dinv, nN, H, IN);
  k_agg<1, 0><<<nAgg, 256, 0, stream>>>(bufA, ewp, offs, dinv, b1, g1, be1, m1, v1, bufB, nN);
  // layer 2:  h2' = (act1*W2)*dinv ; act2' = BNReLU(dinv*sum h2' + b2)*dinv
  k_gemm<0><<<MT, 512, 0, stream>>>(bufB, Wt2, bufA, nullptr, dinv, nN, H, H, 1);
  k_agg<1, 1><<<nAgg, 256, 0, stream>>>(bufA, ewp, offs, dinv, b2, g2, be2, m2, v2, bufB, nN);
  // layer 3 (reordered):  agg3 = dinv*sum act2' ; out = agg3*W3 + b3
  k_agg<0, 0><<<nAgg, 256, 0, stream>>>(bufB, ewp, offs, dinv, nullptr, nullptr, nullptr,
                                        nullptr, nullptr, bufA, nN);
  k_gemm<1><<<MT * 2, 512, 0, stream>>>(bufA, Wt3, d_out, b3, nullptr, nN, OUT, H, 2);
}

// Round 10
// 687.877 us; speedup vs baseline: 1.2144x; 1.2144x over previous
//
#include <hip/hip_runtime.h>
#include <hip/hip_bf16.h>
#include <stdint.h>

typedef __attribute__((ext_vector_type(4))) float f32x4;
typedef __attribute__((ext_vector_type(8))) short s16x8;
typedef __attribute__((ext_vector_type(4))) unsigned short u16x4;

#define EPSBN 1e-5f

__device__ __forceinline__ float bf2f(unsigned short u) {
  union { unsigned int i; float f; } w; w.i = ((unsigned int)u) << 16; return w.f;
}
__device__ __forceinline__ unsigned short f2bf(float f) {
  __hip_bfloat16 h = __float2bfloat16(f);   // RNE
  unsigned short u; __builtin_memcpy(&u, &h, 2); return u;
}
__device__ __forceinline__ void gld_lds16(const void* g, void* l) {
  __builtin_amdgcn_global_load_lds(
      (const __attribute__((address_space(1))) void*)(g),
      (__attribute__((address_space(3))) void*)(l), 16, 0, 0);
}

// ---------------- graph prep ----------------
__global__ void k_count(const int* __restrict__ dst, unsigned* __restrict__ deg, int E) {
  int i = blockIdx.x * 256 + threadIdx.x;
  if (i < E) atomicAdd(&deg[dst[i]], 1u);
}
__global__ void k_prep2(const unsigned* __restrict__ deg, float* __restrict__ dinv,
                        unsigned* __restrict__ bsum, int n) {
  __shared__ unsigned s[256];
  int t = threadIdx.x, i = blockIdx.x * 256 + t;
  unsigned d = (i < n) ? deg[i] + 1u : 0u;
  if (i < n) dinv[i] = rsqrtf((float)d);
  s[t] = d;
  __syncthreads();
  for (int st = 128; st > 0; st >>= 1) {
    if (t < st) s[t] += s[t + st];
    __syncthreads();
  }
  if (t == 0) bsum[blockIdx.x] = s[0];
}
__global__ void k_scan_top(const unsigned* __restrict__ bsum, unsigned* __restrict__ bpre,
                           int nb, unsigned* __restrict__ offs, int n) {
  __shared__ unsigned s[256];
  int t = threadIdx.x;
  unsigned v = (t < nb) ? bsum[t] : 0u;
  s[t] = v; __syncthreads();
  for (int d = 1; d < 256; d <<= 1) {
    unsigned a = (t >= d) ? s[t - d] : 0u;
    __syncthreads();
    s[t] += a;
    __syncthreads();
  }
  bpre[t] = s[t] - v;                    // exclusive
  if (t == 255) offs[n] = s[255];        // total = E + n
}
__global__ void k_scan_fin(const unsigned* __restrict__ deg, const unsigned* __restrict__ bpre,
                           unsigned* __restrict__ offs, unsigned* __restrict__ cur, int n) {
  __shared__ unsigned s[256];
  int t = threadIdx.x, i = blockIdx.x * 256 + t;
  unsigned v = (i < n) ? deg[i] + 1u : 0u;
  s[t] = v; __syncthreads();
  for (int d = 1; d < 256; d <<= 1) {
    unsigned a = (t >= d) ? s[t - d] : 0u;
    __syncthreads();
    s[t] += a;
    __syncthreads();
  }
  if (i < n) {
    unsigned o = bpre[blockIdx.x] + s[t] - v;
    offs[i] = o; cur[i] = o;
  }
}
__global__ void k_fill(const int* __restrict__ src, const int* __restrict__ dst,
                       unsigned* __restrict__ cur, unsigned short* __restrict__ ewp,
                       int E, int n) {
  int i = blockIdx.x * 256 + threadIdx.x;
  int s, d;
  if (i < E)          { s = src[i]; d = dst[i]; }
  else if (i < E + n) { s = d = i - E; }        // self-loop
  else return;
  unsigned p = atomicAdd(&cur[d], 1u);
  ewp[p] = (unsigned short)s;
}
__global__ __launch_bounds__(256) void k_sortw(const unsigned* __restrict__ offs,
                                               unsigned short* __restrict__ ewp, int nN) {
  int wv = (blockIdx.x * 256 + threadIdx.x) >> 6;
  int lane = threadIdx.x & 63;
  if (wv >= nN) return;
  unsigned beg = offs[wv], end = offs[wv + 1];
  int len = (int)(end - beg);
  if (len > 64) return;                  // rare: leave unsorted (correct)
  int k = (lane < len) ? (int)ewp[beg + lane] : 0x10000;
#pragma unroll
  for (int size = 2; size <= 64; size <<= 1) {
#pragma unroll
    for (int stride = size >> 1; stride > 0; stride >>= 1) {
      int other = __shfl_xor(k, stride);
      bool up = (lane & size) == 0;
      bool lower = (lane & stride) == 0;
      k = (lower == up) ? min(k, other) : max(k, other);
    }
  }
  if (lane < len) ewp[beg + lane] = (unsigned short)k;
}
__global__ void k_wt3(const float* __restrict__ W1, unsigned short* __restrict__ Wt1,
                      const float* __restrict__ W2, unsigned short* __restrict__ Wt2,
                      const float* __restrict__ W3, unsigned short* __restrict__ Wt3,
                      unsigned short* __restrict__ bufA, unsigned short* __restrict__ bufB,
                      int nN) {
  const int n1 = 256 * 1280, n2 = 256 * 256, n3 = 512 * 256;
  int idx = blockIdx.x * 256 + threadIdx.x;
  if (idx >= n1 + n2 + n3) {
    int z = idx - (n1 + n2 + n3);
    if (z < 256)      bufA[(size_t)nN * 256 + z] = 0;
    else if (z < 512) bufB[(size_t)nN * 256 + (z - 256)] = 0;
    return;
  }
  const float* W; unsigned short* Wt; int K, N;
  if (idx < n1)           { W = W1; Wt = Wt1; K = 1280; N = 256; }
  else if (idx < n1 + n2) { W = W2; Wt = Wt2; K = 256;  N = 256; idx -= n1; }
  else                    { W = W3; Wt = Wt3; K = 256;  N = 500; idx -= n1 + n2; }
  int nn = idx / K, k = idx - nn * K;
  float v = (nn < N) ? W[(size_t)k * N + nn] : 0.f;
  Wt[idx] = f2bf(v);
}

#define BM 128
#define BK 64

// ---------------- GEMM (bf16 A): 128x128 tile, 256 thr, 4 blocks/CU (R8-proven) ----------------
// OUTMODE 0: bf16 out *dinv[row]; 1: fp32 out + bias.
template<int OUTMODE>
__global__ __launch_bounds__(256, 4) void k_gemm(
    const unsigned short* __restrict__ Au, const unsigned short* __restrict__ Bt,
    void* __restrict__ Coutv, const float* __restrict__ bias,
    const float* __restrict__ dinv, int M, int N, int K, int MT, int NT)
{
  __shared__ __align__(16) unsigned short As[BM * BK];
  __shared__ __align__(16) unsigned short Bs[128 * BK];

  int d = blockIdx.x;
  int xc = d & 7, sb = d >> 3;
  int nt = sb % NT, mt = (sb / NT) * 8 + xc;
  if (mt >= MT) return;
  int m0 = mt * BM, n0 = nt * 128;

  int tid = threadIdx.x, lane = tid & 63, wave = tid >> 6;
  int wm = wave >> 1, wn = wave & 1;
  int l15 = lane & 15, l4 = lane >> 4;

  f32x4 acc[4][4];
#pragma unroll
  for (int i = 0; i < 4; ++i)
#pragma unroll
    for (int j = 0; j < 4; ++j) acc[i][j] = 0.f;

  int srow[4], scg[4];
#pragma unroll
  for (int i = 0; i < 4; ++i) {
    int ci = (wave + 4 * i) * 64 + lane;
    srow[i] = ci >> 3;                         // 8 chunks per 128B row
    scg[i] = (ci & 7) ^ (srow[i] & 7);         // pre-swizzled source chunk
  }

  int nk = K / BK;
  for (int kt = 0; kt < nk; ++kt) {
    __syncthreads();
#pragma unroll
    for (int i = 0; i < 4; ++i) {
      int gr = m0 + srow[i]; gr = gr < M ? gr : M - 1;
      gld_lds16(Au + (size_t)gr * K + kt * BK + scg[i] * 8, As + (wave + 4 * i) * 512);
    }
#pragma unroll
    for (int i = 0; i < 4; ++i) {
      int gn = n0 + srow[i];
      gld_lds16(Bt + (size_t)gn * K + kt * BK + scg[i] * 8, Bs + (wave + 4 * i) * 512);
    }
    __syncthreads();

#pragma unroll
    for (int ks = 0; ks < 2; ++ks) {
      s16x8 af[4], bf[4];
#pragma unroll
      for (int f = 0; f < 4; ++f) {
        int r = wm * 64 + f * 16 + l15;
        int ca = (ks * 4 + l4) ^ (r & 7);
        af[f] = *(const s16x8*)(As + r * 64 + ca * 8);
        int nloc = wn * 64 + f * 16 + l15;
        int cb = (ks * 4 + l4) ^ (nloc & 7);
        bf[f] = *(const s16x8*)(Bs + nloc * 64 + cb * 8);
      }
#pragma unroll
      for (int fm = 0; fm < 4; ++fm)
#pragma unroll
        for (int fn = 0; fn < 4; ++fn)
          acc[fm][fn] = __builtin_amdgcn_mfma_f32_16x16x32_bf16(af[fm], bf[fn], acc[fm][fn], 0, 0, 0);
    }
  }

#pragma unroll
  for (int fm = 0; fm < 4; ++fm) {
#pragma unroll
    for (int r = 0; r < 4; ++r) {
      int row = m0 + wm * 64 + fm * 16 + l4 * 4 + r;
      float dsc = (OUTMODE == 0 && row < M) ? dinv[row] : 0.f;
#pragma unroll
      for (int fn = 0; fn < 4; ++fn) {
        int col = n0 + wn * 64 + fn * 16 + l15;
        if (row < M && col < N) {
          if (OUTMODE == 1)
            ((float*)Coutv)[(size_t)row * N + col] = acc[fm][fn][r] + bias[col];
          else
            ((unsigned short*)Coutv)[(size_t)row * N + col] = f2bf(acc[fm][fn][r] * dsc);
        }
      }
    }
  }
}

// ------- GEMM layer1: 128x256 (NT=1), 512 thr, A fp32 staged once, full-bank swizzle -------
__global__ __launch_bounds__(512, 4) void k_gemmF(
    const float* __restrict__ Af, const unsigned short* __restrict__ Bt,
    unsigned short* __restrict__ Cout, const float* __restrict__ dinv,
    int M, int N, int K)
{
  __shared__ __align__(16) float As[BM * BK];            // 32 KB fp32
  __shared__ __align__(16) unsigned short Bs[256 * BK];  // 32 KB

  int mt = blockIdx.x;
  int m0 = mt * BM, n0 = 0;

  int tid = threadIdx.x, lane = tid & 63, wave = tid >> 6;
  int wm = wave >> 2, wn = wave & 3;
  int l15 = lane & 15, l4 = lane >> 4;

  f32x4 acc[4][4];
#pragma unroll
  for (int i = 0; i < 4; ++i)
#pragma unroll
    for (int j = 0; j < 4; ++j) acc[i][j] = 0.f;

  // A: 2048 chunks (16 per 256B row), 4/thread; swizzle covers bit0 for full bank spread
  int arow[4], acs[4];
#pragma unroll
  for (int i = 0; i < 4; ++i) {
    int ci = i * 512 + tid;
    arow[i] = ci >> 4;
    int s = ((arow[i] & 7) << 1) | ((arow[i] >> 3) & 1);
    acs[i] = (ci & 15) ^ s;
  }
  int brow[4], bcg[4];
#pragma unroll
  for (int i = 0; i < 4; ++i) {
    int ci = i * 512 + tid;
    brow[i] = ci >> 3;
    bcg[i] = (ci & 7) ^ (brow[i] & 7);
  }

  int nk = K / BK;
  for (int kt = 0; kt < nk; ++kt) {
    __syncthreads();
#pragma unroll
    for (int i = 0; i < 4; ++i) {
      int gr = m0 + arow[i]; gr = gr < M ? gr : M - 1;
      gld_lds16(Af + (size_t)gr * K + kt * BK + acs[i] * 4,
                As + (size_t)(i * 512 + wave * 64) * 4);
    }
#pragma unroll
    for (int i = 0; i < 4; ++i) {
      int gn = n0 + brow[i];
      gld_lds16(Bt + (size_t)gn * K + kt * BK + bcg[i] * 8,
                Bs + (size_t)(i * 512 + wave * 64) * 8);
    }
    __syncthreads();

#pragma unroll
    for (int ks = 0; ks < 2; ++ks) {
      s16x8 af[4], bf[4];
#pragma unroll
      for (int f = 0; f < 4; ++f) {
        int r = wm * 64 + f * 16 + l15;
        int s = ((r & 7) << 1) | ((r >> 3) & 1);
        int gc0 = ks * 8 + 2 * l4;
        f32x4 a0 = *(const f32x4*)(As + r * 64 + (gc0 ^ s) * 4);
        f32x4 a1 = *(const f32x4*)(As + r * 64 + ((gc0 + 1) ^ s) * 4);
        s16x8 pk;
        pk[0] = (short)f2bf(a0[0]); pk[1] = (short)f2bf(a0[1]);
        pk[2] = (short)f2bf(a0[2]); pk[3] = (short)f2bf(a0[3]);
        pk[4] = (short)f2bf(a1[0]); pk[5] = (short)f2bf(a1[1]);
        pk[6] = (short)f2bf(a1[2]); pk[7] = (short)f2bf(a1[3]);
        af[f] = pk;
        int nloc = wn * 64 + f * 16 + l15;
        int cb = (ks * 4 + l4) ^ (nloc & 7);
        bf[f] = *(const s16x8*)(Bs + nloc * 64 + cb * 8);
      }
#pragma unroll
      for (int fm = 0; fm < 4; ++fm)
#pragma unroll
        for (int fn = 0; fn < 4; ++fn)
          acc[fm][fn] = __builtin_amdgcn_mfma_f32_16x16x32_bf16(af[fm], bf[fn], acc[fm][fn], 0, 0, 0);
    }
  }

#pragma unroll
  for (int fm = 0; fm < 4; ++fm) {
#pragma unroll
    for (int r = 0; r < 4; ++r) {
      int row = m0 + wm * 64 + fm * 16 + l4 * 4 + r;
      float dsc = (row < M) ? dinv[row] : 0.f;
#pragma unroll
      for (int fn = 0; fn < 4; ++fn) {
        int col = n0 + wn * 64 + fn * 16 + l15;
        if (row < M && col < N)
          Cout[(size_t)row * N + col] = f2bf(acc[fm][fn][r] * dsc);
      }
    }
  }
}

// -------- aggregation (C=256), 16-deep pipelined row gathers, pre-scaled h --------
template<int BNRELU, int SCALEOUT>
__global__ __launch_bounds__(256) void k_agg(
    const unsigned short* __restrict__ h, const unsigned short* __restrict__ ewp,
    const unsigned* __restrict__ offs, const float* __restrict__ dinv,
    const float* __restrict__ bias, const float* __restrict__ gam,
    const float* __restrict__ bet, const float* __restrict__ mea,
    const float* __restrict__ var, unsigned short* __restrict__ outp, int nN)
{
  int wave = threadIdx.x >> 6, lane = threadIdx.x & 63;
  int v = blockIdx.x * 4 + wave;
  if (v >= nN) return;
  unsigned beg = offs[v], end = offs[v + 1];
  int len = (int)(end - beg);
  float dv = dinv[v];
  const unsigned short* hb = h + lane * 4;
  float a0 = 0, a1 = 0, a2 = 0, a3 = 0;

  for (int base = 0; base < len; base += 64) {
    int m = min(64, len - base);
    int myp = (lane < m) ? (int)ewp[beg + base + lane] : nN;   // pad -> zero row
    int ng = (m + 15) >> 4;

    u16x4 q[16];
#pragma unroll
    for (int r = 0; r < 16; ++r) {
      int s = __shfl(myp, r);
      q[r] = *(const u16x4*)(hb + (size_t)s * 256);
    }
    for (int g = 1; g < ng; ++g) {
      u16x4 q2[16];
#pragma unroll
      for (int r = 0; r < 16; ++r) {
        int s = __shfl(myp, g * 16 + r);
        q2[r] = *(const u16x4*)(hb + (size_t)s * 256);
      }
#pragma unroll
      for (int r = 0; r < 16; ++r) {
        a0 += bf2f(q[r][0]); a1 += bf2f(q[r][1]);
        a2 += bf2f(q[r][2]); a3 += bf2f(q[r][3]);
      }
#pragma unroll
      for (int r = 0; r < 16; ++r) q[r] = q2[r];
    }
#pragma unroll
    for (int r = 0; r < 16; ++r) {
      a0 += bf2f(q[r][0]); a1 += bf2f(q[r][1]);
      a2 += bf2f(q[r][2]); a3 += bf2f(q[r][3]);
    }
  }

  float va[4] = {a0, a1, a2, a3};
  int ch0 = lane * 4;
#pragma unroll
  for (int j = 0; j < 4; ++j) {
    int ch = ch0 + j;
    float val = va[j] * dv;                    // dst-side norm factor
    if (BNRELU) {
      val += bias[ch];
      val = (val - mea[ch]) * rsqrtf(var[ch] + EPSBN) * gam[ch] + bet[ch];
      val = fmaxf(val, 0.f);
    }
    if (SCALEOUT) val *= dv;                   // pre-scale for the NEXT aggregation
    outp[(size_t)v * 256 + ch] = f2bf(val);
  }
}

// ---------------- launch ----------------
extern "C" void kernel_launch(void* const* d_in, const int* in_sizes, int n_in,
                              void* d_out, int out_size, void* d_ws, size_t ws_size,
                              hipStream_t stream) {
  const float* x   = (const float*)d_in[0];
  const int*   ei  = (const int*)d_in[1];
  const float* W1  = (const float*)d_in[2];
  const float* b1  = (const float*)d_in[3];
  const float* g1  = (const float*)d_in[4];
  const float* be1 = (const float*)d_in[5];
  const float* m1  = (const float*)d_in[6];
  const float* v1  = (const float*)d_in[7];
  const float* W2  = (const float*)d_in[8];
  const float* b2  = (const float*)d_in[9];
  const float* g2  = (const float*)d_in[10];
  const float* be2 = (const float*)d_in[11];
  const float* m2  = (const float*)d_in[12];
  const float* v2  = (const float*)d_in[13];
  const float* W3  = (const float*)d_in[14];
  const float* b3  = (const float*)d_in[15];

  const int IN = 1280, H = 256, OUT = 500, OUTP = 512;
  int E  = in_sizes[1] / 2;
  int nN = in_sizes[0] / IN;
  const int* srcI = ei;
  const int* dstI = ei + E;

  char* p = (char*)d_ws;
  auto carve = [&](size_t bytes) { char* r = p; p += (bytes + 511) & ~(size_t)511; return r; };
  unsigned short* Wt1 = (unsigned short*)carve((size_t)H * IN * 2);
  unsigned short* Wt2 = (unsigned short*)carve((size_t)H * H * 2);
  unsigned short* Wt3 = (unsigned short*)carve((size_t)OUTP * H * 2);
  unsigned* deg  = (unsigned*)carve((size_t)nN * 4);
  float*    dinv = (float*)carve((size_t)nN * 4);
  unsigned* offs = (unsigned*)carve((size_t)(nN + 1) * 4);
  unsigned* cur  = (unsigned*)carve((size_t)nN * 4);
  unsigned* bsum = (unsigned*)carve(256 * 4);
  unsigned* bpre = (unsigned*)carve(256 * 4);
  unsigned short* ewp = (unsigned short*)carve((size_t)(E + nN) * 2);
  unsigned short* bufA = (unsigned short*)carve((size_t)(nN + 1) * H * 2);  // +1 zero pad row
  unsigned short* bufB = (unsigned short*)carve((size_t)(nN + 1) * H * 2);

  hipMemsetAsync(deg, 0, (size_t)nN * 4, stream);

  int NB = (nN + 255) / 256;
  k_count<<<(E + 255) / 256, 256, 0, stream>>>(dstI, deg, E);
  k_prep2<<<NB, 256, 0, stream>>>(deg, dinv, bsum, nN);
  k_scan_top<<<1, 256, 0, stream>>>(bsum, bpre, NB, offs, nN);
  k_scan_fin<<<NB, 256, 0, stream>>>(deg, bpre, offs, cur, nN);
  k_fill<<<(E + nN + 255) / 256, 256, 0, stream>>>(srcI, dstI, cur, ewp, E, nN);
  k_sortw<<<(nN + 3) / 4, 256, 0, stream>>>(offs, ewp, nN);
  k_wt3<<<(256 * 1280 + 256 * 256 + 512 * 256 + 512 + 255) / 256, 256, 0, stream>>>(
      W1, Wt1, W2, Wt2, W3, Wt3, bufA, bufB, nN);

  int MT = (nN + BM - 1) / BM;          // 391
  int mg = (MT + 7) / 8;                // 49
  int nAgg = (nN + 3) / 4;

  // layer 1:  h1' = (x*W1)*dinv ; act1 = BNReLU(dinv*sum h1' + b1)
  k_gemmF<<<MT, 512, 0, stream>>>(x, Wt1, bufA, dinv, nN, H, IN);
  k_agg<1, 0><<<nAgg, 256, 0, stream>>>(bufA, ewp, offs, dinv, b1, g1, be1, m1, v1, bufB, nN);
  // layer 2:  h2' = (act1*W2)*dinv ; act2' = BNReLU(dinv*sum h2' + b2)*dinv
  k_gemm<0><<<mg * 8 * 2, 256, 0, stream>>>(bufB, Wt2, bufA, nullptr, dinv, nN, H, H, MT, 2);
  k_agg<1, 1><<<nAgg, 256, 0, stream>>>(bufA, ewp, offs, dinv, b2, g2, be2, m2, v2, bufB, nN);
  // layer 3 (reordered):  agg3 = dinv*sum act2' ; out = agg3*W3 + b3
  k_agg<0, 0><<<nAgg, 256, 0, stream>>>(bufB, ewp, offs, dinv, nullptr, nullptr, nullptr,
                                        nullptr, nullptr, bufA, nN);
  k_gemm<1><<<mg * 8 * 4, 256, 0, stream>>>(bufA, Wt3, d_out, b3, nullptr, nN, OUT, H, MT, 4);
}

// Round 11
// 682.837 us; speedup vs baseline: 1.2233x; 1.0074x over previous
//
#include <hip/hip_runtime.h>
#include <hip/hip_bf16.h>
#include <stdint.h>

typedef __attribute__((ext_vector_type(4))) float f32x4;
typedef __attribute__((ext_vector_type(8))) short s16x8;
typedef __attribute__((ext_vector_type(4))) unsigned short u16x4;

#define EPSBN 1e-5f

__device__ __forceinline__ float bf2f(unsigned short u) {
  union { unsigned int i; float f; } w; w.i = ((unsigned int)u) << 16; return w.f;
}
__device__ __forceinline__ unsigned short f2bf(float f) {
  __hip_bfloat16 h = __float2bfloat16(f);   // RNE
  unsigned short u; __builtin_memcpy(&u, &h, 2); return u;
}
__device__ __forceinline__ void gld_lds16(const void* g, void* l) {
  __builtin_amdgcn_global_load_lds(
      (const __attribute__((address_space(1))) void*)(g),
      (__attribute__((address_space(3))) void*)(l), 16, 0, 0);
}

// ---------------- graph prep ----------------
__global__ void k_count(const int* __restrict__ dst, unsigned* __restrict__ deg, int E) {
  int i = blockIdx.x * 256 + threadIdx.x;
  if (i < E) atomicAdd(&deg[dst[i]], 1u);
}
__global__ void k_prep2(const unsigned* __restrict__ deg, float* __restrict__ dinv,
                        unsigned* __restrict__ bsum, int n) {
  __shared__ unsigned s[256];
  int t = threadIdx.x, i = blockIdx.x * 256 + t;
  unsigned d = (i < n) ? deg[i] + 1u : 0u;
  if (i < n) dinv[i] = rsqrtf((float)d);
  s[t] = d;
  __syncthreads();
  for (int st = 128; st > 0; st >>= 1) {
    if (t < st) s[t] += s[t + st];
    __syncthreads();
  }
  if (t == 0) bsum[blockIdx.x] = s[0];
}
__global__ void k_scan_top(const unsigned* __restrict__ bsum, unsigned* __restrict__ bpre,
                           int nb, unsigned* __restrict__ offs, int n) {
  __shared__ unsigned s[256];
  int t = threadIdx.x;
  unsigned v = (t < nb) ? bsum[t] : 0u;
  s[t] = v; __syncthreads();
  for (int d = 1; d < 256; d <<= 1) {
    unsigned a = (t >= d) ? s[t - d] : 0u;
    __syncthreads();
    s[t] += a;
    __syncthreads();
  }
  bpre[t] = s[t] - v;                    // exclusive
  if (t == 255) offs[n] = s[255];        // total = E + n
}
__global__ void k_scan_fin(const unsigned* __restrict__ deg, const unsigned* __restrict__ bpre,
                           unsigned* __restrict__ offs, unsigned* __restrict__ cur, int n) {
  __shared__ unsigned s[256];
  int t = threadIdx.x, i = blockIdx.x * 256 + t;
  unsigned v = (i < n) ? deg[i] + 1u : 0u;
  s[t] = v; __syncthreads();
  for (int d = 1; d < 256; d <<= 1) {
    unsigned a = (t >= d) ? s[t - d] : 0u;
    __syncthreads();
    s[t] += a;
    __syncthreads();
  }
  if (i < n) {
    unsigned o = bpre[blockIdx.x] + s[t] - v;
    offs[i] = o; cur[i] = o;
  }
}
__global__ void k_fill(const int* __restrict__ src, const int* __restrict__ dst,
                       unsigned* __restrict__ cur, unsigned short* __restrict__ ewp,
                       int E, int n) {
  int i = blockIdx.x * 256 + threadIdx.x;
  int s, d;
  if (i < E)          { s = src[i]; d = dst[i]; }
  else if (i < E + n) { s = d = i - E; }        // self-loop
  else return;
  unsigned p = atomicAdd(&cur[d], 1u);
  ewp[p] = (unsigned short)s;
}
__global__ __launch_bounds__(256) void k_sortw(const unsigned* __restrict__ offs,
                                               unsigned short* __restrict__ ewp, int nN) {
  int wv = (blockIdx.x * 256 + threadIdx.x) >> 6;
  int lane = threadIdx.x & 63;
  if (wv >= nN) return;
  unsigned beg = offs[wv], end = offs[wv + 1];
  int len = (int)(end - beg);
  if (len > 64) return;                  // rare: leave unsorted (correct)
  int k = (lane < len) ? (int)ewp[beg + lane] : 0x10000;
#pragma unroll
  for (int size = 2; size <= 64; size <<= 1) {
#pragma unroll
    for (int stride = size >> 1; stride > 0; stride >>= 1) {
      int other = __shfl_xor(k, stride);
      bool up = (lane & size) == 0;
      bool lower = (lane & stride) == 0;
      k = (lower == up) ? min(k, other) : max(k, other);
    }
  }
  if (lane < len) ewp[beg + lane] = (unsigned short)k;
}
__global__ void k_wt3(const float* __restrict__ W1, unsigned short* __restrict__ Wt1,
                      const float* __restrict__ W2, unsigned short* __restrict__ Wt2,
                      const float* __restrict__ W3, unsigned short* __restrict__ Wt3,
                      unsigned short* __restrict__ bufA, unsigned short* __restrict__ bufB,
                      int nN) {
  const int n1 = 256 * 1280, n2 = 256 * 256, n3 = 512 * 256;
  int idx = blockIdx.x * 256 + threadIdx.x;
  if (idx >= n1 + n2 + n3) {
    int z = idx - (n1 + n2 + n3);
    if (z < 256)      bufA[(size_t)nN * 256 + z] = 0;
    else if (z < 512) bufB[(size_t)nN * 256 + (z - 256)] = 0;
    return;
  }
  const float* W; unsigned short* Wt; int K, N;
  if (idx < n1)           { W = W1; Wt = Wt1; K = 1280; N = 256; }
  else if (idx < n1 + n2) { W = W2; Wt = Wt2; K = 256;  N = 256; idx -= n1; }
  else                    { W = W3; Wt = Wt3; K = 256;  N = 500; idx -= n1 + n2; }
  int nn = idx / K, k = idx - nn * K;
  float v = (nn < N) ? W[(size_t)k * N + nn] : 0.f;
  Wt[idx] = f2bf(v);
}

#define BM 128
#define BK 64

// ---------------- GEMM (bf16 A): 128x128 tile, 256 thr, 4 blocks/CU (R8-proven) ----------------
// OUTMODE 0: bf16 out *dinv[row]; 1: fp32 out + bias.
template<int OUTMODE>
__global__ __launch_bounds__(256, 4) void k_gemm(
    const unsigned short* __restrict__ Au, const unsigned short* __restrict__ Bt,
    void* __restrict__ Coutv, const float* __restrict__ bias,
    const float* __restrict__ dinv, int M, int N, int K, int MT, int NT)
{
  __shared__ __align__(16) unsigned short As[BM * BK];
  __shared__ __align__(16) unsigned short Bs[128 * BK];

  int d = blockIdx.x;
  int xc = d & 7, sb = d >> 3;
  int nt = sb % NT, mt = (sb / NT) * 8 + xc;
  if (mt >= MT) return;
  int m0 = mt * BM, n0 = nt * 128;

  int tid = threadIdx.x, lane = tid & 63, wave = tid >> 6;
  int wm = wave >> 1, wn = wave & 1;
  int l15 = lane & 15, l4 = lane >> 4;

  f32x4 acc[4][4];
#pragma unroll
  for (int i = 0; i < 4; ++i)
#pragma unroll
    for (int j = 0; j < 4; ++j) acc[i][j] = 0.f;

  int srow[4], scg[4];
#pragma unroll
  for (int i = 0; i < 4; ++i) {
    int ci = (wave + 4 * i) * 64 + lane;
    srow[i] = ci >> 3;                         // 8 chunks per 128B row
    scg[i] = (ci & 7) ^ (srow[i] & 7);         // pre-swizzled source chunk
  }

  int nk = K / BK;
  for (int kt = 0; kt < nk; ++kt) {
    __syncthreads();
#pragma unroll
    for (int i = 0; i < 4; ++i) {
      int gr = m0 + srow[i]; gr = gr < M ? gr : M - 1;
      gld_lds16(Au + (size_t)gr * K + kt * BK + scg[i] * 8, As + (wave + 4 * i) * 512);
    }
#pragma unroll
    for (int i = 0; i < 4; ++i) {
      int gn = n0 + srow[i];
      gld_lds16(Bt + (size_t)gn * K + kt * BK + scg[i] * 8, Bs + (wave + 4 * i) * 512);
    }
    __syncthreads();

#pragma unroll
    for (int ks = 0; ks < 2; ++ks) {
      s16x8 af[4], bf[4];
#pragma unroll
      for (int f = 0; f < 4; ++f) {
        int r = wm * 64 + f * 16 + l15;
        int ca = (ks * 4 + l4) ^ (r & 7);
        af[f] = *(const s16x8*)(As + r * 64 + ca * 8);
        int nloc = wn * 64 + f * 16 + l15;
        int cb = (ks * 4 + l4) ^ (nloc & 7);
        bf[f] = *(const s16x8*)(Bs + nloc * 64 + cb * 8);
      }
#pragma unroll
      for (int fm = 0; fm < 4; ++fm)
#pragma unroll
        for (int fn = 0; fn < 4; ++fn)
          acc[fm][fn] = __builtin_amdgcn_mfma_f32_16x16x32_bf16(af[fm], bf[fn], acc[fm][fn], 0, 0, 0);
    }
  }

#pragma unroll
  for (int fm = 0; fm < 4; ++fm) {
#pragma unroll
    for (int r = 0; r < 4; ++r) {
      int row = m0 + wm * 64 + fm * 16 + l4 * 4 + r;
      float dsc = (OUTMODE == 0 && row < M) ? dinv[row] : 0.f;
#pragma unroll
      for (int fn = 0; fn < 4; ++fn) {
        int col = n0 + wn * 64 + fn * 16 + l15;
        if (row < M && col < N) {
          if (OUTMODE == 1)
            ((float*)Coutv)[(size_t)row * N + col] = acc[fm][fn][r] + bias[col];
          else
            ((unsigned short*)Coutv)[(size_t)row * N + col] = f2bf(acc[fm][fn][r] * dsc);
        }
      }
    }
  }
}

// ------- GEMM layer1: 128x256 (NT=1), 512 thr, A fp32, BK=32, 2-phase double buffer -------
// Pipeline: stage(kt+1) issued BEFORE compute(kt); single vmcnt-drain barrier per step.
#define FBK 32
#define ASZ (BM * FBK)     // 4096 floats = 16 KB
#define BSZ (256 * FBK)    // 8192 bf16  = 16 KB

__global__ __launch_bounds__(512, 4) void k_gemmF(
    const float* __restrict__ Af, const unsigned short* __restrict__ Bt,
    unsigned short* __restrict__ Cout, const float* __restrict__ dinv,
    int M, int N, int K)
{
  __shared__ __align__(16) float As[2 * ASZ];            // 32 KB fp32 (2 buf)
  __shared__ __align__(16) unsigned short Bs[2 * BSZ];   // 32 KB bf16 (2 buf)

  int mt = blockIdx.x;
  int m0 = mt * BM;

  int tid = threadIdx.x, lane = tid & 63, wave = tid >> 6;
  int wm = wave >> 2, wn = wave & 3;
  int l15 = lane & 15, l4 = lane >> 4;

  f32x4 acc[4][4];
#pragma unroll
  for (int i = 0; i < 4; ++i)
#pragma unroll
    for (int j = 0; j < 4; ++j) acc[i][j] = 0.f;

  // A: 1024 chunks (8 per 128B row), 2/thread; source pre-swizzle cr^(row&7)
  int arow[2], acs[2];
#pragma unroll
  for (int i = 0; i < 2; ++i) {
    int ci = i * 512 + tid;
    arow[i] = ci >> 3;
    acs[i] = (ci & 7) ^ (arow[i] & 7);
  }
  // B: 1024 chunks (4 per 64B row), 2/thread; source pre-swizzle cr^((row>>1)&3)
  int brow[2], bcs[2];
#pragma unroll
  for (int i = 0; i < 2; ++i) {
    int ci = i * 512 + tid;
    brow[i] = ci >> 2;
    bcs[i] = (ci & 3) ^ ((brow[i] >> 1) & 3);
  }
  int gra[2];
#pragma unroll
  for (int i = 0; i < 2; ++i) {
    int gr = m0 + arow[i]; gra[i] = gr < M ? gr : M - 1;
  }

  int nk = K / FBK;                       // 40
  int cur = 0;

  // prologue: stage tile 0 into buf 0
#pragma unroll
  for (int i = 0; i < 2; ++i)
    gld_lds16(Af + (size_t)gra[i] * K + acs[i] * 4, As + (size_t)(i * 512 + wave * 64) * 4);
#pragma unroll
  for (int i = 0; i < 2; ++i)
    gld_lds16(Bt + (size_t)brow[i] * K + bcs[i] * 8, Bs + (size_t)(i * 512 + wave * 64) * 8);
  __syncthreads();

  for (int kt = 0; kt < nk; ++kt) {
    // issue next-tile loads first (fly during compute)
    if (kt + 1 < nk) {
      int nxt = cur ^ 1;
      int kb = (kt + 1) * FBK;
#pragma unroll
      for (int i = 0; i < 2; ++i)
        gld_lds16(Af + (size_t)gra[i] * K + kb + acs[i] * 4,
                  As + (size_t)nxt * ASZ + (size_t)(i * 512 + wave * 64) * 4);
#pragma unroll
      for (int i = 0; i < 2; ++i)
        gld_lds16(Bt + (size_t)brow[i] * K + kb + bcs[i] * 8,
                  Bs + (size_t)nxt * BSZ + (size_t)(i * 512 + wave * 64) * 8);
    }
    // compute current buffer
    const float* Ab = As + (size_t)cur * ASZ;
    const unsigned short* Bb = Bs + (size_t)cur * BSZ;
    s16x8 af[4], bf[4];
#pragma unroll
    for (int f = 0; f < 4; ++f) {
      int r = wm * 64 + f * 16 + l15;
      int sA = r & 7;
      int g0 = 2 * l4;
      f32x4 a0 = *(const f32x4*)(Ab + r * 32 + (g0 ^ sA) * 4);
      f32x4 a1 = *(const f32x4*)(Ab + r * 32 + ((g0 + 1) ^ sA) * 4);
      s16x8 pk;
      pk[0] = (short)f2bf(a0[0]); pk[1] = (short)f2bf(a0[1]);
      pk[2] = (short)f2bf(a0[2]); pk[3] = (short)f2bf(a0[3]);
      pk[4] = (short)f2bf(a1[0]); pk[5] = (short)f2bf(a1[1]);
      pk[6] = (short)f2bf(a1[2]); pk[7] = (short)f2bf(a1[3]);
      af[f] = pk;
      int nloc = wn * 64 + f * 16 + l15;
      int cb = l4 ^ ((nloc >> 1) & 3);
      bf[f] = *(const s16x8*)(Bb + nloc * 32 + cb * 8);
    }
#pragma unroll
    for (int fm = 0; fm < 4; ++fm)
#pragma unroll
      for (int fn = 0; fn < 4; ++fn)
        acc[fm][fn] = __builtin_amdgcn_mfma_f32_16x16x32_bf16(af[fm], bf[fn], acc[fm][fn], 0, 0, 0);
    // single drain point per step: next tile lands, all waves sync
    __syncthreads();
    cur ^= 1;
  }

#pragma unroll
  for (int fm = 0; fm < 4; ++fm) {
#pragma unroll
    for (int r = 0; r < 4; ++r) {
      int row = m0 + wm * 64 + fm * 16 + l4 * 4 + r;
      float dsc = (row < M) ? dinv[row] : 0.f;
#pragma unroll
      for (int fn = 0; fn < 4; ++fn) {
        int col = wn * 64 + fn * 16 + l15;
        if (row < M && col < N)
          Cout[(size_t)row * N + col] = f2bf(acc[fm][fn][r] * dsc);
      }
    }
  }
}

// -------- aggregation (C=256), 16-deep pipelined row gathers, pre-scaled h --------
template<int BNRELU, int SCALEOUT>
__global__ __launch_bounds__(256) void k_agg(
    const unsigned short* __restrict__ h, const unsigned short* __restrict__ ewp,
    const unsigned* __restrict__ offs, const float* __restrict__ dinv,
    const float* __restrict__ bias, const float* __restrict__ gam,
    const float* __restrict__ bet, const float* __restrict__ mea,
    const float* __restrict__ var, unsigned short* __restrict__ outp, int nN)
{
  int wave = threadIdx.x >> 6, lane = threadIdx.x & 63;
  int v = blockIdx.x * 4 + wave;
  if (v >= nN) return;
  unsigned beg = offs[v], end = offs[v + 1];
  int len = (int)(end - beg);
  float dv = dinv[v];
  const unsigned short* hb = h + lane * 4;
  float a0 = 0, a1 = 0, a2 = 0, a3 = 0;

  for (int base = 0; base < len; base += 64) {
    int m = min(64, len - base);
    int myp = (lane < m) ? (int)ewp[beg + base + lane] : nN;   // pad -> zero row
    int ng = (m + 15) >> 4;

    u16x4 q[16];
#pragma unroll
    for (int r = 0; r < 16; ++r) {
      int s = __shfl(myp, r);
      q[r] = *(const u16x4*)(hb + (size_t)s * 256);
    }
    for (int g = 1; g < ng; ++g) {
      u16x4 q2[16];
#pragma unroll
      for (int r = 0; r < 16; ++r) {
        int s = __shfl(myp, g * 16 + r);
        q2[r] = *(const u16x4*)(hb + (size_t)s * 256);
      }
#pragma unroll
      for (int r = 0; r < 16; ++r) {
        a0 += bf2f(q[r][0]); a1 += bf2f(q[r][1]);
        a2 += bf2f(q[r][2]); a3 += bf2f(q[r][3]);
      }
#pragma unroll
      for (int r = 0; r < 16; ++r) q[r] = q2[r];
    }
#pragma unroll
    for (int r = 0; r < 16; ++r) {
      a0 += bf2f(q[r][0]); a1 += bf2f(q[r][1]);
      a2 += bf2f(q[r][2]); a3 += bf2f(q[r][3]);
    }
  }

  float va[4] = {a0, a1, a2, a3};
  int ch0 = lane * 4;
#pragma unroll
  for (int j = 0; j < 4; ++j) {
    int ch = ch0 + j;
    float val = va[j] * dv;                    // dst-side norm factor
    if (BNRELU) {
      val += bias[ch];
      val = (val - mea[ch]) * rsqrtf(var[ch] + EPSBN) * gam[ch] + bet[ch];
      val = fmaxf(val, 0.f);
    }
    if (SCALEOUT) val *= dv;                   // pre-scale for the NEXT aggregation
    outp[(size_t)v * 256 + ch] = f2bf(val);
  }
}

// ---------------- launch ----------------
extern "C" void kernel_launch(void* const* d_in, const int* in_sizes, int n_in,
                              void* d_out, int out_size, void* d_ws, size_t ws_size,
                              hipStream_t stream) {
  const float* x   = (const float*)d_in[0];
  const int*   ei  = (const int*)d_in[1];
  const float* W1  = (const float*)d_in[2];
  const float* b1  = (const float*)d_in[3];
  const float* g1  = (const float*)d_in[4];
  const float* be1 = (const float*)d_in[5];
  const float* m1  = (const float*)d_in[6];
  const float* v1  = (const float*)d_in[7];
  const float* W2  = (const float*)d_in[8];
  const float* b2  = (const float*)d_in[9];
  const float* g2  = (const float*)d_in[10];
  const float* be2 = (const float*)d_in[11];
  const float* m2  = (const float*)d_in[12];
  const float* v2  = (const float*)d_in[13];
  const float* W3  = (const float*)d_in[14];
  const float* b3  = (const float*)d_in[15];

  const int IN = 1280, H = 256, OUT = 500, OUTP = 512;
  int E  = in_sizes[1] / 2;
  int nN = in_sizes[0] / IN;
  const int* srcI = ei;
  const int* dstI = ei + E;

  char* p = (char*)d_ws;
  auto carve = [&](size_t bytes) { char* r = p; p += (bytes + 511) & ~(size_t)511; return r; };
  unsigned short* Wt1 = (unsigned short*)carve((size_t)H * IN * 2);
  unsigned short* Wt2 = (unsigned short*)carve((size_t)H * H * 2);
  unsigned short* Wt3 = (unsigned short*)carve((size_t)OUTP * H * 2);
  unsigned* deg  = (unsigned*)carve((size_t)nN * 4);
  float*    dinv = (float*)carve((size_t)nN * 4);
  unsigned* offs = (unsigned*)carve((size_t)(nN + 1) * 4);
  unsigned* cur  = (unsigned*)carve((size_t)nN * 4);
  unsigned* bsum = (unsigned*)carve(256 * 4);
  unsigned* bpre = (unsigned*)carve(256 * 4);
  unsigned short* ewp = (unsigned short*)carve((size_t)(E + nN) * 2);
  unsigned short* bufA = (unsigned short*)carve((size_t)(nN + 1) * H * 2);  // +1 zero pad row
  unsigned short* bufB = (unsigned short*)carve((size_t)(nN + 1) * H * 2);

  hipMemsetAsync(deg, 0, (size_t)nN * 4, stream);

  int NB = (nN + 255) / 256;
  k_count<<<(E + 255) / 256, 256, 0, stream>>>(dstI, deg, E);
  k_prep2<<<NB, 256, 0, stream>>>(deg, dinv, bsum, nN);
  k_scan_top<<<1, 256, 0, stream>>>(bsum, bpre, NB, offs, nN);
  k_scan_fin<<<NB, 256, 0, stream>>>(deg, bpre, offs, cur, nN);
  k_fill<<<(E + nN + 255) / 256, 256, 0, stream>>>(srcI, dstI, cur, ewp, E, nN);
  k_sortw<<<(nN + 3) / 4, 256, 0, stream>>>(offs, ewp, nN);
  k_wt3<<<(256 * 1280 + 256 * 256 + 512 * 256 + 512 + 255) / 256, 256, 0, stream>>>(
      W1, Wt1, W2, Wt2, W3, Wt3, bufA, bufB, nN);

  int MT = (nN + BM - 1) / BM;          // 391
  int mg = (MT + 7) / 8;                // 49
  int nAgg = (nN + 3) / 4;

  // layer 1:  h1' = (x*W1)*dinv ; act1 = BNReLU(dinv*sum h1' + b1)
  k_gemmF<<<MT, 512, 0, stream>>>(x, Wt1, bufA, dinv, nN, H, IN);
  k_agg<1, 0><<<nAgg, 256, 0, stream>>>(bufA, ewp, offs, dinv, b1, g1, be1, m1, v1, bufB, nN);
  // layer 2:  h2' = (act1*W2)*dinv ; act2' = BNReLU(dinv*sum h2' + b2)*dinv
  k_gemm<0><<<mg * 8 * 2, 256, 0, stream>>>(bufB, Wt2, bufA, nullptr, dinv, nN, H, H, MT, 2);
  k_agg<1, 1><<<nAgg, 256, 0, stream>>>(bufA, ewp, offs, dinv, b2, g2, be2, m2, v2, bufB, nN);
  // layer 3 (reordered):  agg3 = dinv*sum act2' ; out = agg3*W3 + b3
  k_agg<0, 0><<<nAgg, 256, 0, stream>>>(bufB, ewp, offs, dinv, nullptr, nullptr, nullptr,
                                        nullptr, nullptr, bufA, nN);
  k_gemm<1><<<mg * 8 * 4, 256, 0, stream>>>(bufA, Wt3, d_out, b3, nullptr, nN, OUT, H, MT, 4);
}